// Round 2
// baseline (386.133 us; speedup 1.0000x reference)
//
#include <hip/hip_runtime.h>

// DeformableConv1d: B=32, C=64, L=16384, COUT=64, K=1.
// R2: both 1x1 convs on MFMA (16x16x32 bf16, split hi/lo = 3 passes for ~fp32
// precision). x staged in LDS as packed (bf16_hi | bf16_lo<<16) words; gather
// served from LDS with +-32 halo (global fallback for rare far offsets).

#define BDIM 256
#define BB   32
#define CC   64
#define LL   16384
#define TL   128                 // l-tile per block
#define HH   32                  // gather halo
#define RS   (TL + 2*HH + 4)     // 196 words/row; 196*4=784 B, 16B-aligned

#define PERM_HI 0x05040100u      // (pa.lo16) | (pb.lo16 << 16)
#define PERM_LO 0x07060302u      // (pa.hi16) | (pb.hi16 << 16)

typedef __attribute__((ext_vector_type(8))) short s8;
typedef __attribute__((ext_vector_type(4))) float f4;

union U32F { unsigned u; float f; };

// RNE float->bf16 (bits), split x = hi + lo; pack as hi | lo<<16.
static __device__ __forceinline__ unsigned packsplit(float f) {
    U32F v; v.f = f;
    unsigned hi = (v.u + 0x7fffu + ((v.u >> 16) & 1u)) >> 16;
    U32F hf; hf.u = hi << 16;
    U32F lv; lv.f = f - hf.f;
    unsigned lo = (lv.u + 0x7fffu + ((lv.u >> 16) & 1u)) >> 16;
    return hi | (lo << 16);
}

static __device__ __forceinline__ float unpackf(unsigned w) {
    U32F a; a.u = w << 16;           // hi
    U32F b; b.u = w & 0xffff0000u;   // lo
    return a.f + b.f;
}

union S8U { unsigned u[4]; s8 v; };

// A-fragment (weights) direct from global fp32: lane holds W[16*wv+n][k..k+7]
static __device__ __forceinline__ void load_a_frags(const float* __restrict__ wp,
                                                    int wv, int n, int q,
                                                    s8* ahi, s8* alo) {
    #pragma unroll
    for (int ks = 0; ks < 2; ++ks) {
        const float* base = wp + (16 * wv + n) * 64 + ks * 32 + q * 8;
        float4 w0 = *(const float4*)base;
        float4 w1 = *(const float4*)(base + 4);
        float vals[8] = {w0.x, w0.y, w0.z, w0.w, w1.x, w1.y, w1.z, w1.w};
        S8U h, l;
        #pragma unroll
        for (int p = 0; p < 4; ++p) {
            unsigned pa = packsplit(vals[2 * p]);
            unsigned pb = packsplit(vals[2 * p + 1]);
            h.u[p] = __builtin_amdgcn_perm(pb, pa, PERM_HI);
            l.u[p] = __builtin_amdgcn_perm(pb, pa, PERM_LO);
        }
        ahi[ks] = h.v; alo[ks] = l.v;
    }
}

__global__ __launch_bounds__(BDIM)
void deform_conv1d_mfma(const float* __restrict__ x,
                        const float* __restrict__ offw,
                        const float* __restrict__ offb,
                        const float* __restrict__ regw,
                        const float* __restrict__ regb,
                        float* __restrict__ out) {
    __shared__ unsigned Xs[CC * RS];   // packed hi|lo words, rows=channel

    const int tid = threadIdx.x;
    const int lg0 = blockIdx.x * TL;
    const int b   = blockIdx.y;
    const size_t xb = (size_t)b * CC * LL;

    // ---------------- stage x tile (+halo) as packed words ----------------
    const bool interior = (lg0 >= HH) && (lg0 + TL + HH <= LL);
    if (interior) {
        const float* xc = x + xb + lg0;
        #pragma unroll
        for (int k2 = 0; k2 < 8; ++k2) {          // core: 32 float4 per row
            int i = tid + k2 * BDIM;
            int row = i >> 5, f = i & 31;
            float4 v = *(const float4*)(xc + (size_t)row * LL + f * 4);
            uint4 pw = make_uint4(packsplit(v.x), packsplit(v.y),
                                  packsplit(v.z), packsplit(v.w));
            *(uint4*)(&Xs[row * RS + HH + f * 4]) = pw;
        }
        const float* xl = x + xb + lg0 - HH;
        #pragma unroll
        for (int k2 = 0; k2 < 2; ++k2) {          // left halo: 8 float4/row
            int i = tid + k2 * BDIM;
            int row = i >> 3, f = i & 7;
            float4 v = *(const float4*)(xl + (size_t)row * LL + f * 4);
            uint4 pw = make_uint4(packsplit(v.x), packsplit(v.y),
                                  packsplit(v.z), packsplit(v.w));
            *(uint4*)(&Xs[row * RS + f * 4]) = pw;
        }
        const float* xr = x + xb + lg0 + TL;
        #pragma unroll
        for (int k2 = 0; k2 < 2; ++k2) {          // right halo
            int i = tid + k2 * BDIM;
            int row = i >> 3, f = i & 7;
            float4 v = *(const float4*)(xr + (size_t)row * LL + f * 4);
            uint4 pw = make_uint4(packsplit(v.x), packsplit(v.y),
                                  packsplit(v.z), packsplit(v.w));
            *(uint4*)(&Xs[row * RS + HH + TL + f * 4]) = pw;
        }
    } else {                                      // edge tiles: clamped scalar
        for (int idx = tid; idx < CC * (TL + 2 * HH); idx += BDIM) {
            int row = idx / (TL + 2 * HH);
            int col = idx - row * (TL + 2 * HH);
            int g = lg0 - HH + col;
            g = min(max(g, 0), LL - 1);
            Xs[row * RS + col] = packsplit(x[xb + (size_t)row * LL + g]);
        }
    }
    __syncthreads();

    const int wv   = tid >> 6;     // wave id: output rows [16*wv, 16*wv+16)
    const int lane = tid & 63;
    const int q    = lane >> 4;    // quad
    const int n    = lane & 15;    // column within 16-tile / A-row

    // ---------------- matmul 1: offsets = Wo * x + bo ----------------
    s8 ahi[2], alo[2];
    load_a_frags(offw, wv, n, q, ahi, alo);

    f4 acc[8];
    {
        float4 bo = *(const float4*)(offb + 16 * wv + 4 * q);
        #pragma unroll
        for (int nt = 0; nt < 8; ++nt) acc[nt] = (f4){bo.x, bo.y, bo.z, bo.w};
    }
    #pragma unroll
    for (int nt = 0; nt < 8; ++nt) {
        const int colbase = HH + nt * 16 + n;
        #pragma unroll
        for (int ks = 0; ks < 2; ++ks) {
            unsigned wds[8];
            #pragma unroll
            for (int j = 0; j < 8; ++j) {          // quad-rotated k order
                int jj = (j + 2 * q) & 7;
                int k = ks * 32 + q * 8 + jj;
                wds[jj] = Xs[k * RS + colbase];
            }
            S8U bh, bl;
            #pragma unroll
            for (int p = 0; p < 4; ++p) {
                bh.u[p] = __builtin_amdgcn_perm(wds[2 * p + 1], wds[2 * p], PERM_HI);
                bl.u[p] = __builtin_amdgcn_perm(wds[2 * p + 1], wds[2 * p], PERM_LO);
            }
            acc[nt] = __builtin_amdgcn_mfma_f32_16x16x32_bf16(ahi[ks], bh.v, acc[nt], 0, 0, 0);
            acc[nt] = __builtin_amdgcn_mfma_f32_16x16x32_bf16(ahi[ks], bl.v, acc[nt], 0, 0, 0);
            acc[nt] = __builtin_amdgcn_mfma_f32_16x16x32_bf16(alo[ks], bh.v, acc[nt], 0, 0, 0);
        }
    }

    // ---------------- gather + lerp (acc := x_deform) ----------------
    #pragma unroll
    for (int nt = 0; nt < 8; ++nt) {
        #pragma unroll
        for (int reg = 0; reg < 4; ++reg) {
            const int c = 16 * wv + 4 * q + reg;   // C/D layout row
            float pos = (float)(lg0 + nt * 16 + n) + acc[nt][reg];
            pos = fminf(fmaxf(pos, 0.0f), (float)(LL - 1));
            float fl = floorf(pos);
            float frac = pos - fl;
            int i0 = (int)fl;
            int di = frac > 0.0f ? 1 : 0;
            unsigned u = (unsigned)(i0 - lg0 + HH);
            float x0, x1;
            if (u <= (unsigned)(TL + 2 * HH - 2)) {
                x0 = unpackf(Xs[c * RS + u]);
                x1 = unpackf(Xs[c * RS + u + di]);
            } else {                                // rare far offset
                const float* xr = x + xb + (size_t)c * LL;
                x0 = xr[i0]; x1 = xr[i0 + di];
            }
            acc[nt][reg] = x0 + frac * (x1 - x0);
        }
    }

    __syncthreads();   // all reads of x tile done before overwrite
    #pragma unroll
    for (int nt = 0; nt < 8; ++nt) {
        #pragma unroll
        for (int reg = 0; reg < 4; ++reg) {
            const int c = 16 * wv + 4 * q + reg;
            Xs[c * RS + HH + nt * 16 + n] = packsplit(acc[nt][reg]);
        }
    }
    __syncthreads();

    // ---------------- matmul 2: out = Wr * x_deform + br ----------------
    load_a_frags(regw, wv, n, q, ahi, alo);
    {
        float4 br = *(const float4*)(regb + 16 * wv + 4 * q);
        #pragma unroll
        for (int nt = 0; nt < 8; ++nt) acc[nt] = (f4){br.x, br.y, br.z, br.w};
    }
    #pragma unroll
    for (int nt = 0; nt < 8; ++nt) {
        const int colbase = HH + nt * 16 + n;
        #pragma unroll
        for (int ks = 0; ks < 2; ++ks) {
            unsigned wds[8];
            #pragma unroll
            for (int j = 0; j < 8; ++j) {
                int jj = (j + 2 * q) & 7;
                int k = ks * 32 + q * 8 + jj;
                wds[jj] = Xs[k * RS + colbase];
            }
            S8U bh, bl;
            #pragma unroll
            for (int p = 0; p < 4; ++p) {
                bh.u[p] = __builtin_amdgcn_perm(wds[2 * p + 1], wds[2 * p], PERM_HI);
                bl.u[p] = __builtin_amdgcn_perm(wds[2 * p + 1], wds[2 * p], PERM_LO);
            }
            acc[nt] = __builtin_amdgcn_mfma_f32_16x16x32_bf16(ahi[ks], bh.v, acc[nt], 0, 0, 0);
            acc[nt] = __builtin_amdgcn_mfma_f32_16x16x32_bf16(ahi[ks], bl.v, acc[nt], 0, 0, 0);
            acc[nt] = __builtin_amdgcn_mfma_f32_16x16x32_bf16(alo[ks], bh.v, acc[nt], 0, 0, 0);
        }
    }

    // ---------------- store ----------------
    float* op = out + (size_t)b * CC * LL + lg0;
    #pragma unroll
    for (int nt = 0; nt < 8; ++nt) {
        #pragma unroll
        for (int reg = 0; reg < 4; ++reg) {
            op[(size_t)(16 * wv + 4 * q + reg) * LL + nt * 16 + n] = acc[nt][reg];
        }
    }
}

extern "C" void kernel_launch(void* const* d_in, const int* in_sizes, int n_in,
                              void* d_out, int out_size, void* d_ws, size_t ws_size,
                              hipStream_t stream) {
    const float* x    = (const float*)d_in[0];   // [32,64,16384]
    const float* offw = (const float*)d_in[1];   // [64,64,1]
    const float* offb = (const float*)d_in[2];   // [64]
    const float* regw = (const float*)d_in[3];   // [64,64,1]
    const float* regb = (const float*)d_in[4];   // [64]
    float* out = (float*)d_out;                  // [32,64,16384]

    dim3 grid(LL / TL, BB);
    deform_conv1d_mfma<<<grid, dim3(BDIM), 0, stream>>>(x, offw, offb, regw, regb, out);
}

// Round 3
// 262.204 us; speedup vs baseline: 1.4726x; 1.4726x over previous
//
#include <hip/hip_runtime.h>

// DeformableConv1d: B=32, C=64, L=16384, COUT=64, K=1.
// R3: x staged ONCE in LDS, transposed [l][ci], packed (bf16_hi | bf16_lo<<16)
// words, row stride 68 words (b128-aligned). Serves matmul1 B-frags
// (contiguous ds_read_b128) AND the gather (1 word = ~fp32 x). x_deform in
// single-bf16 [l][ci] (stride 72) -> matmul2 B-frag = one raw ds_read_b128.
// matmul1 = 3-pass split bf16 (offset precision); matmul2 = 1-pass bf16.
// Exact-frac: frac(l+off) == frac(off) since l is integer.

#define BDIM 256
#define BB   32
#define CC   64
#define LL   16384
#define TL   64                  // l-tile per block
#define HH   8                   // gather halo (offsets max ~3.2 over 33M)
#define ROWS (TL + 2*HH)         // 80 staged l-rows
#define RSW  68                  // Xt row stride (words): 272 B, 16B-aligned
#define RSD  72                  // Xd row stride (bf16): 144 B, 16B-aligned

#define PERM_HI 0x05040100u      // (a.lo16) | (b.lo16 << 16)
#define PERM_LO 0x07060302u      // (a.hi16) | (b.hi16 << 16)

typedef __attribute__((ext_vector_type(8))) short s8;
typedef __attribute__((ext_vector_type(4))) float f4;

union U32F { unsigned u; float f; };
union S8U  { unsigned u[4]; s8 v; };

// RNE float->bf16 bits
static __device__ __forceinline__ unsigned bfround(float f) {
    U32F v; v.f = f;
    return (v.u + 0x7fffu + ((v.u >> 16) & 1u)) >> 16;
}
// split x = hi + lo, pack hi | lo<<16
static __device__ __forceinline__ unsigned packsplit(float f) {
    U32F v; v.f = f;
    unsigned hi = (v.u + 0x7fffu + ((v.u >> 16) & 1u)) >> 16;
    U32F hf; hf.u = hi << 16;
    U32F lv; lv.f = f - hf.f;
    unsigned lo = (lv.u + 0x7fffu + ((lv.u >> 16) & 1u)) >> 16;
    return hi | (lo << 16);
}
static __device__ __forceinline__ float unpackf(unsigned w) {
    U32F a; a.u = w << 16;
    U32F b; b.u = w & 0xffff0000u;
    return a.f + b.f;
}

// split A-frag (weights) from global fp32: lane holds W[row][k0..k0+7]
static __device__ __forceinline__ void load_a_split(const float* __restrict__ wp,
                                                    int row, int ks, int q,
                                                    s8* ahi, s8* alo) {
    const float* base = wp + row * 64 + ks * 32 + q * 8;
    float4 w0 = *(const float4*)base;
    float4 w1 = *(const float4*)(base + 4);
    float vals[8] = {w0.x, w0.y, w0.z, w0.w, w1.x, w1.y, w1.z, w1.w};
    S8U h, l;
    #pragma unroll
    for (int p = 0; p < 4; ++p) {
        unsigned pa = packsplit(vals[2 * p]);
        unsigned pb = packsplit(vals[2 * p + 1]);
        h.u[p] = __builtin_amdgcn_perm(pb, pa, PERM_HI);
        l.u[p] = __builtin_amdgcn_perm(pb, pa, PERM_LO);
    }
    *ahi = h.v; *alo = l.v;
}
// single-bf16 A-frag
static __device__ __forceinline__ s8 load_a_bf16(const float* __restrict__ wp,
                                                 int row, int ks, int q) {
    const float* base = wp + row * 64 + ks * 32 + q * 8;
    float4 w0 = *(const float4*)base;
    float4 w1 = *(const float4*)(base + 4);
    float vals[8] = {w0.x, w0.y, w0.z, w0.w, w1.x, w1.y, w1.z, w1.w};
    S8U r;
    #pragma unroll
    for (int p = 0; p < 4; ++p)
        r.u[p] = bfround(vals[2 * p]) | (bfround(vals[2 * p + 1]) << 16);
    return r.v;
}

__global__ __launch_bounds__(BDIM)
void deform_conv1d_r3(const float* __restrict__ x,
                      const float* __restrict__ offw,
                      const float* __restrict__ offb,
                      const float* __restrict__ regw,
                      const float* __restrict__ regb,
                      float* __restrict__ out) {
    __shared__ __align__(16) unsigned Xt[ROWS * RSW];          // 21.8 KB
    __shared__ __align__(16) unsigned short Xd[TL * RSD];      // 9.2 KB

    const int tid = threadIdx.x;
    const int bx  = blockIdx.x;
    const int lg0 = bx * TL;
    const int b   = blockIdx.y;
    const size_t xb = (size_t)b * CC * LL;

    // ------------- stage x -> Xt[l][c] packed, via register 4x4 transpose ---
    if (bx >= 1 && bx <= (LL / TL) - 2) {
        // 16 c-blocks x 20 l-blocks of 4x4
        for (int i = tid; i < 320; i += BDIM) {
            int cb = i / 20, lb = i - cb * 20;
            int c0 = cb * 4;
            int l0 = lg0 - HH + lb * 4;              // >= 56, +3 <= L-1
            const float* p = x + xb + (size_t)c0 * LL + l0;
            float4 v0 = *(const float4*)(p);
            float4 v1 = *(const float4*)(p + LL);
            float4 v2 = *(const float4*)(p + 2 * LL);
            float4 v3 = *(const float4*)(p + 3 * LL);
            uint4 w;
            w.x = packsplit(v0.x); w.y = packsplit(v1.x);
            w.z = packsplit(v2.x); w.w = packsplit(v3.x);
            *(uint4*)(&Xt[(lb * 4 + 0) * RSW + c0]) = w;
            w.x = packsplit(v0.y); w.y = packsplit(v1.y);
            w.z = packsplit(v2.y); w.w = packsplit(v3.y);
            *(uint4*)(&Xt[(lb * 4 + 1) * RSW + c0]) = w;
            w.x = packsplit(v0.z); w.y = packsplit(v1.z);
            w.z = packsplit(v2.z); w.w = packsplit(v3.z);
            *(uint4*)(&Xt[(lb * 4 + 2) * RSW + c0]) = w;
            w.x = packsplit(v0.w); w.y = packsplit(v1.w);
            w.z = packsplit(v2.w); w.w = packsplit(v3.w);
            *(uint4*)(&Xt[(lb * 4 + 3) * RSW + c0]) = w;
        }
    } else {                                          // edge blocks: clamped
        for (int i = tid; i < ROWS * CC; i += BDIM) {
            int r = i >> 6, c = i & 63;
            int g = lg0 - HH + r;
            g = min(max(g, 0), LL - 1);
            Xt[r * RSW + c] = packsplit(x[xb + (size_t)c * LL + g]);
        }
    }
    __syncthreads();

    const int wv   = tid >> 6;       // wave -> output-row tile [16wv,16wv+16)
    const int lane = tid & 63;
    const int q    = lane >> 4;
    const int n    = lane & 15;

    // ------------- matmul 1: offsets = Wo * x + bo  (3-pass split) ----------
    s8 ahi[2], alo[2];
    load_a_split(offw, 16 * wv + n, 0, q, &ahi[0], &alo[0]);
    load_a_split(offw, 16 * wv + n, 1, q, &ahi[1], &alo[1]);

    f4 acc[4];
    {
        float4 bo = *(const float4*)(offb + 16 * wv + 4 * q);
        #pragma unroll
        for (int nt = 0; nt < 4; ++nt) acc[nt] = (f4){bo.x, bo.y, bo.z, bo.w};
    }
    #pragma unroll
    for (int nt = 0; nt < 4; ++nt) {
        const int row = HH + 16 * nt + n;             // l within Xt
        #pragma unroll
        for (int ks = 0; ks < 2; ++ks) {
            const unsigned* bp = &Xt[row * RSW + ks * 32 + q * 8];
            uint4 wlo = *(const uint4*)(bp);
            uint4 whi = *(const uint4*)(bp + 4);
            unsigned wd[8] = {wlo.x, wlo.y, wlo.z, wlo.w,
                              whi.x, whi.y, whi.z, whi.w};
            S8U bh, bl;
            #pragma unroll
            for (int p = 0; p < 4; ++p) {
                bh.u[p] = __builtin_amdgcn_perm(wd[2 * p + 1], wd[2 * p], PERM_HI);
                bl.u[p] = __builtin_amdgcn_perm(wd[2 * p + 1], wd[2 * p], PERM_LO);
            }
            acc[nt] = __builtin_amdgcn_mfma_f32_16x16x32_bf16(ahi[ks], bh.v, acc[nt], 0, 0, 0);
            acc[nt] = __builtin_amdgcn_mfma_f32_16x16x32_bf16(ahi[ks], bl.v, acc[nt], 0, 0, 0);
            acc[nt] = __builtin_amdgcn_mfma_f32_16x16x32_bf16(alo[ks], bh.v, acc[nt], 0, 0, 0);
        }
    }

    // ------------- gather + lerp (acc := x_deform), exact frac --------------
    #pragma unroll
    for (int nt = 0; nt < 4; ++nt) {
        #pragma unroll
        for (int reg = 0; reg < 4; ++reg) {
            const int c = 16 * wv + 4 * q + reg;      // C/D row
            const int l = lg0 + 16 * nt + n;          // C/D col
            float o  = acc[nt][reg];
            float of = floorf(o);
            float fr = o - of;                         // exact
            int idx  = l + (int)of;
            if (idx < 0)            { idx = 0;      fr = 0.0f; }
            else if (idx >= LL - 1) { idx = LL - 1; fr = 0.0f; }
            int u = idx - lg0 + HH;
            float x0, x1;
            if ((unsigned)u <= (unsigned)(ROWS - 2)) {
                x0 = unpackf(Xt[u * RSW + c]);
                x1 = unpackf(Xt[(u + 1) * RSW + c]);
            } else {                                   // |off|>8: ~never
                const float* xr = x + xb + (size_t)c * LL;
                x0 = xr[idx];
                x1 = xr[idx + (fr > 0.0f ? 1 : 0)];
            }
            acc[nt][reg] = x0 + fr * (x1 - x0);
        }
    }

    // ------------- x_deform -> Xd[l][c] single bf16 -------------------------
    #pragma unroll
    for (int nt = 0; nt < 4; ++nt) {
        unsigned h0 = bfround(acc[nt][0]);
        unsigned h1 = bfround(acc[nt][1]);
        unsigned h2 = bfround(acc[nt][2]);
        unsigned h3 = bfround(acc[nt][3]);
        uint2 pw;
        pw.x = h0 | (h1 << 16);
        pw.y = h2 | (h3 << 16);
        *(uint2*)(&Xd[(16 * nt + n) * RSD + 16 * wv + 4 * q]) = pw;
    }
    __syncthreads();

    // ------------- matmul 2: out = Wr * x_deform + br  (1-pass bf16) --------
    s8 a2[2];
    a2[0] = load_a_bf16(regw, 16 * wv + n, 0, q);
    a2[1] = load_a_bf16(regw, 16 * wv + n, 1, q);
    {
        float4 br = *(const float4*)(regb + 16 * wv + 4 * q);
        #pragma unroll
        for (int nt = 0; nt < 4; ++nt) acc[nt] = (f4){br.x, br.y, br.z, br.w};
    }
    #pragma unroll
    for (int nt = 0; nt < 4; ++nt) {
        #pragma unroll
        for (int ks = 0; ks < 2; ++ks) {
            s8 bv = *(const s8*)(&Xd[(16 * nt + n) * RSD + ks * 32 + q * 8]);
            acc[nt] = __builtin_amdgcn_mfma_f32_16x16x32_bf16(a2[ks], bv, acc[nt], 0, 0, 0);
        }
    }

    // ------------- store ----------------------------------------------------
    float* op = out + (size_t)b * CC * LL;
    #pragma unroll
    for (int nt = 0; nt < 4; ++nt) {
        #pragma unroll
        for (int reg = 0; reg < 4; ++reg) {
            op[(size_t)(16 * wv + 4 * q + reg) * LL + lg0 + 16 * nt + n] = acc[nt][reg];
        }
    }
}

extern "C" void kernel_launch(void* const* d_in, const int* in_sizes, int n_in,
                              void* d_out, int out_size, void* d_ws, size_t ws_size,
                              hipStream_t stream) {
    const float* x    = (const float*)d_in[0];   // [32,64,16384]
    const float* offw = (const float*)d_in[1];   // [64,64,1]
    const float* offb = (const float*)d_in[2];   // [64]
    const float* regw = (const float*)d_in[3];   // [64,64,1]
    const float* regb = (const float*)d_in[4];   // [64]
    float* out = (float*)d_out;                  // [32,64,16384]

    dim3 grid(LL / TL, BB);
    deform_conv1d_r3<<<grid, dim3(BDIM), 0, stream>>>(x, offw, offb, regw, regb, out);
}